// Round 1
// baseline (865.365 us; speedup 1.0000x reference)
//
#include <hip/hip_runtime.h>
#include <math.h>

typedef _Float16 f16;
typedef _Float16 half8 __attribute__((ext_vector_type(8)));
typedef _Float16 half4v __attribute__((ext_vector_type(4)));
typedef float f32x4 __attribute__((ext_vector_type(4)));

#define NB 8
#define SEQ 4096
#define QDIM 1280
#define CDIM 1024
#define INNER 1280
#define CTX 85
#define CTXP 96

// ---------------- cast x fp32 -> f16 ----------------
__global__ void k_cast(const float* __restrict__ x, f16* __restrict__ xh, int n4) {
  int i = blockIdx.x * blockDim.x + threadIdx.x;
  if (i >= n4) return;
  float4 v = ((const float4*)x)[i];
  half4v o;
  o.x = (f16)v.x; o.y = (f16)v.y; o.z = (f16)v.z; o.w = (f16)v.w;
  *(half4v*)(xh + 4 * (long)i) = o;
}

// ---------------- transpose W [K][Nn] fp32 -> [Nn][K] f16 ----------------
__global__ void k_transpose(const float* __restrict__ in, f16* __restrict__ out, int K, int Nn) {
  __shared__ f16 tile[32][33];
  int n0 = blockIdx.x * 32, k0 = blockIdx.y * 32;
  int tx = threadIdx.x, ty = threadIdx.y;  // 32 x 8
  for (int i = 0; i < 4; i++) {
    int k = k0 + ty + i * 8;
    tile[ty + i * 8][tx] = (f16)in[(long)k * Nn + n0 + tx];
  }
  __syncthreads();
  for (int i = 0; i < 4; i++) {
    int n = n0 + ty + i * 8;
    out[(long)n * K + k0 + tx] = tile[tx][ty + i * 8];
  }
}

// ---------------- fg mask: exact integer bicubic-!=0 ----------------
// scale=4 => t=0.5 always; weights (-3,19,19,-3)/32, taps 4o..4o+3 (no clamping).
__global__ void k_fg(const int* __restrict__ mask, unsigned char* __restrict__ fg) {
  int id = blockIdx.x * 256 + threadIdx.x;  // 8*4096
  int b = id >> 12, o = (id >> 6) & 63, p = id & 63;
  const int* mb = mask + (long)b * 65536;
  const int w[4] = {-3, 19, 19, -3};
  int s = 0;
  for (int dh = 0; dh < 4; dh++) {
    const int* row = mb + (4 * o + dh) * 256 + 4 * p;
    int rs = -3 * row[0] + 19 * row[1] + 19 * row[2] - 3 * row[3];
    s += w[dh] * rs;
  }
  fg[id] = (s != 0) ? 1 : 0;
}

// ---------------- K/V projection: ctx[b][85][1024] @ WT -> kpad / vT ----------------
// grid (10 ntiles, 8 b, 2 kv), 256 threads
__global__ __launch_bounds__(256) void k_kvproj(const float* __restrict__ ctx,
    const f16* __restrict__ WkT, const f16* __restrict__ WvT,
    f16* __restrict__ kpad, f16* __restrict__ vT) {
  int nb0 = blockIdx.x * 128;
  int b = blockIdx.y;
  int kv = blockIdx.z;
  const f16* WT = kv ? WvT : WkT;
  __shared__ __attribute__((aligned(16))) f16 Clds[CTXP][40];
  __shared__ __attribute__((aligned(16))) f16 Blds[128][40];
  int tid = threadIdx.x;
  int lane = tid & 63, w = tid >> 6;
  int ln = lane & 15, qd = lane >> 4;
  f32x4 acc[6][2] = {};
  for (int k0 = 0; k0 < CDIM; k0 += 32) {
    for (int i = tid; i < CTXP * 32; i += 256) {
      int j = i >> 5, kk = i & 31;
      float v = (j < CTX) ? ctx[((long)b * CTX + j) * CDIM + k0 + kk] : 0.f;
      Clds[j][kk] = (f16)v;
    }
    for (int c = tid; c < 128 * 4; c += 256) {
      int n = c >> 2, kc = (c & 3) * 8;
      *(half8*)&Blds[n][kc] = *(const half8*)&WT[(long)(nb0 + n) * CDIM + k0 + kc];
    }
    __syncthreads();
    half8 bfr[2];
    for (int nt = 0; nt < 2; nt++) bfr[nt] = *(half8*)&Blds[w * 32 + nt * 16 + ln][qd * 8];
    for (int mt = 0; mt < 6; mt++) {
      half8 af = *(half8*)&Clds[mt * 16 + ln][qd * 8];
      for (int nt = 0; nt < 2; nt++)
        acc[mt][nt] = __builtin_amdgcn_mfma_f32_16x16x32_f16(af, bfr[nt], acc[mt][nt], 0, 0, 0);
    }
    __syncthreads();
  }
  for (int mt = 0; mt < 6; mt++)
    for (int nt = 0; nt < 2; nt++) {
      int n = nb0 + w * 32 + nt * 16 + ln;
      if (kv == 0) {
        for (int r = 0; r < 4; r++) {
          int j = mt * 16 + qd * 4 + r;
          kpad[((long)b * CTXP + j) * INNER + n] = (f16)acc[mt][nt][r];
        }
      } else {
        half4v pv;
        for (int r = 0; r < 4; r++) pv[r] = (f16)acc[mt][nt][r];
        *(half4v*)&vT[((long)b * INNER + n) * CTXP + mt * 16 + qd * 4] = pv;
      }
    }
}

// ---------------- big GEMM: A[M][K] f16 @ Bt[N][K] f16 -> out [M][1280] ----------------
// 128x128 tile, BK=64, 256 threads (4 waves as 2x2 of 64x64)
template <int OUT_F32>
__global__ __launch_bounds__(256) void k_gemm(const f16* __restrict__ A,
    const f16* __restrict__ Bt, const float* __restrict__ bias,
    f16* __restrict__ outh, float* __restrict__ outf, int K) {
  __shared__ __attribute__((aligned(16))) f16 Alds[128][72];
  __shared__ __attribute__((aligned(16))) f16 Blds[128][72];
  int tid = threadIdx.x;
  int lane = tid & 63, w = tid >> 6;
  int wr = w >> 1, wc = w & 1;
  int ln = lane & 15, qd = lane >> 4;
  long m0 = (long)blockIdx.x * 128;
  int n0 = blockIdx.y * 128;
  f32x4 acc[4][4] = {};
  for (int k0 = 0; k0 < K; k0 += 64) {
    for (int i = 0; i < 4; i++) {
      int c = tid + i * 256;  // 0..1023
      int row = c >> 3, kc = (c & 7) * 8;
      *(half8*)&Alds[row][kc] = *(const half8*)&A[(m0 + row) * K + k0 + kc];
      *(half8*)&Blds[row][kc] = *(const half8*)&Bt[(long)(n0 + row) * K + k0 + kc];
    }
    __syncthreads();
    for (int s = 0; s < 2; s++) {
      half8 af[4], bf[4];
      for (int mt = 0; mt < 4; mt++) af[mt] = *(half8*)&Alds[wr * 64 + mt * 16 + ln][s * 32 + qd * 8];
      for (int nt = 0; nt < 4; nt++) bf[nt] = *(half8*)&Blds[wc * 64 + nt * 16 + ln][s * 32 + qd * 8];
      for (int mt = 0; mt < 4; mt++)
        for (int nt = 0; nt < 4; nt++)
          acc[mt][nt] = __builtin_amdgcn_mfma_f32_16x16x32_f16(af[mt], bf[nt], acc[mt][nt], 0, 0, 0);
    }
    __syncthreads();
  }
  for (int mt = 0; mt < 4; mt++) {
    long mrow = m0 + wr * 64 + mt * 16 + qd * 4;
    for (int nt = 0; nt < 4; nt++) {
      int n = n0 + wc * 64 + nt * 16 + ln;
      float bv = OUT_F32 ? bias[n] : 0.f;
      for (int r = 0; r < 4; r++) {
        if (OUT_F32) outf[(mrow + r) * INNER + n] = acc[mt][nt][r] + bv;
        else         outh[(mrow + r) * INNER + n] = (f16)acc[mt][nt][r];
      }
    }
  }
}

// ---------------- fused masked attention ----------------
// grid (64 row-blocks, 20 heads, 8 batch), 256 threads; wave w handles rows w*16..+15
__global__ __launch_bounds__(256) void k_attn(const f16* __restrict__ q,
    const f16* __restrict__ kpad, const f16* __restrict__ vT,
    const unsigned char* __restrict__ fg, f16* __restrict__ ao) {
  int mb = blockIdx.x;
  int h = blockIdx.y;
  int b = blockIdx.z;
  __shared__ __attribute__((aligned(16))) f16 Klds[CTXP][72];
  __shared__ __attribute__((aligned(16))) f16 Vlds[64][104];
  __shared__ __attribute__((aligned(16))) f16 Plds[4][16][104];
  int tid = threadIdx.x, lane = tid & 63, w = tid >> 6;
  int ln = lane & 15, qd = lane >> 4;

  for (int c = tid; c < CTXP * 8; c += 256) {
    int j = c >> 3, kc = (c & 7) * 8;
    *(half8*)&Klds[j][kc] = *(const half8*)&kpad[((long)b * CTXP + j) * INNER + h * 64 + kc];
  }
  for (int c = tid; c < 64 * 12; c += 256) {
    int d = c / 12, jc = (c % 12) * 8;
    *(half8*)&Vlds[d][jc] = *(const half8*)&vT[((long)b * INNER + h * 64 + d) * CTXP + jc];
  }
  __syncthreads();

  long mg = (long)b * SEQ + mb * 64 + w * 16 + ln;  // A-layout row for this lane
  half8 qf[2];
  for (int s = 0; s < 2; s++)
    qf[s] = *(const half8*)&q[mg * INNER + h * 64 + s * 32 + qd * 8];

  f32x4 sacc[6] = {};
  for (int s = 0; s < 2; s++)
    for (int nt = 0; nt < 6; nt++) {
      half8 bf = *(half8*)&Klds[nt * 16 + ln][s * 32 + qd * 8];
      sacc[nt] = __builtin_amdgcn_mfma_f32_16x16x32_f16(qf[s], bf, sacc[nt], 0, 0, 0);
    }

  // softmax over 96 cols (85 real), C-layout rows = qd*4+r
  unsigned int fgw = *(const unsigned int*)&fg[(long)b * SEQ + mb * 64 + w * 16 + qd * 4];
  const float scale = 0.125f;
  for (int r = 0; r < 4; r++) {
    bool f = ((fgw >> (8 * r)) & 0xff) != 0;
    float vals[6];
    bool oks[6];
    float mx = -1e30f;
    for (int nt = 0; nt < 6; nt++) {
      int j = nt * 16 + ln;
      bool ok = (j < 77) || (j < 81 ? f : (j < 85 ? !f : false));
      float v = sacc[nt][r] * scale;
      vals[nt] = v; oks[nt] = ok;
      if (ok) mx = fmaxf(mx, v);
    }
    for (int d = 1; d < 16; d <<= 1) mx = fmaxf(mx, __shfl_xor(mx, d, 64));
    float sum = 0.f, p[6];
    for (int nt = 0; nt < 6; nt++) {
      p[nt] = oks[nt] ? __expf(vals[nt] - mx) : 0.f;
      sum += p[nt];
    }
    for (int d = 1; d < 16; d <<= 1) sum += __shfl_xor(sum, d, 64);
    float inv = 1.f / sum;
    for (int nt = 0; nt < 6; nt++)
      Plds[w][qd * 4 + r][nt * 16 + ln] = (f16)(p[nt] * inv);
  }
  __syncthreads();

  f32x4 oacc[4] = {};
  for (int ks = 0; ks < 3; ks++) {
    half8 pf = *(half8*)&Plds[w][ln][ks * 32 + qd * 8];
    for (int ntd = 0; ntd < 4; ntd++) {
      half8 vf = *(half8*)&Vlds[ntd * 16 + ln][ks * 32 + qd * 8];
      oacc[ntd] = __builtin_amdgcn_mfma_f32_16x16x32_f16(pf, vf, oacc[ntd], 0, 0, 0);
    }
  }
  long mg2 = (long)b * SEQ + mb * 64 + w * 16 + qd * 4;
  for (int ntd = 0; ntd < 4; ntd++)
    for (int r = 0; r < 4; r++)
      ao[(mg2 + r) * INNER + h * 64 + ntd * 16 + ln] = (f16)oacc[ntd][r];
}

extern "C" void kernel_launch(void* const* d_in, const int* in_sizes, int n_in,
                              void* d_out, int out_size, void* d_ws, size_t ws_size,
                              hipStream_t stream) {
  const float* x   = (const float*)d_in[0];
  const float* ctx = (const float*)d_in[1];
  const float* Wq  = (const float*)d_in[2];
  const float* Wk  = (const float*)d_in[3];
  const float* Wv  = (const float*)d_in[4];
  const float* Wo  = (const float*)d_in[5];
  const float* bo  = (const float*)d_in[6];
  const int*  mask = (const int*)d_in[7];
  float* out = (float*)d_out;

  char* ws = (char*)d_ws;
  size_t off = 0;
  f16* xh  = (f16*)(ws + off); off += 83886080;   // 8*4096*1280 f16
  f16* q   = (f16*)(ws + off); off += 83886080;
  f16* ao  = (f16*)(ws + off); off += 83886080;
  f16* WqT = (f16*)(ws + off); off += 3276800;
  f16* WoT = (f16*)(ws + off); off += 3276800;
  f16* WkT = (f16*)(ws + off); off += 2621440;
  f16* WvT = (f16*)(ws + off); off += 2621440;
  f16* kpad= (f16*)(ws + off); off += 1966080;    // [8][96][1280]
  f16* vT  = (f16*)(ws + off); off += 1966080;    // [8][1280][96]
  unsigned char* fg = (unsigned char*)(ws + off); off += 32768;
  if (ws_size < off) return;  // workspace too small: fail loudly via absmax

  k_cast<<<40960, 256, 0, stream>>>(x, xh, 10485760);
  dim3 tb(32, 8);
  k_transpose<<<dim3(1280/32, 1280/32), tb, 0, stream>>>(Wq, WqT, 1280, 1280);
  k_transpose<<<dim3(1280/32, 1024/32), tb, 0, stream>>>(Wk, WkT, 1024, 1280);
  k_transpose<<<dim3(1280/32, 1024/32), tb, 0, stream>>>(Wv, WvT, 1024, 1280);
  k_transpose<<<dim3(1280/32, 1280/32), tb, 0, stream>>>(Wo, WoT, 1280, 1280);
  k_fg<<<128, 256, 0, stream>>>(mask, fg);
  k_kvproj<<<dim3(10, 8, 2), 256, 0, stream>>>(ctx, WkT, WvT, kpad, vT);
  k_gemm<0><<<dim3(256, 10), 256, 0, stream>>>(xh, WqT, nullptr, q, nullptr, 1280);
  k_attn<<<dim3(64, 20, 8), 256, 0, stream>>>(q, kpad, vT, fg, ao);
  k_gemm<1><<<dim3(256, 10), 256, 0, stream>>>(ao, WoT, bo, nullptr, out, 1280);
}

// Round 2
// 858.249 us; speedup vs baseline: 1.0083x; 1.0083x over previous
//
#include <hip/hip_runtime.h>
#include <math.h>

typedef _Float16 f16;
typedef _Float16 half8 __attribute__((ext_vector_type(8)));
typedef _Float16 half4v __attribute__((ext_vector_type(4)));
typedef float f32x4 __attribute__((ext_vector_type(4)));

#define NB 8
#define SEQ 4096
#define QDIM 1280
#define CDIM 1024
#define INNER 1280
#define CTX 85
#define CTXP 96

__device__ __forceinline__ void gload16(const void* g, void* l) {
  __builtin_amdgcn_global_load_lds(
      (const __attribute__((address_space(1))) unsigned int*)g,
      (__attribute__((address_space(3))) unsigned int*)l, 16, 0, 0);
}

// ---------------- cast x fp32 -> f16 (16B stores) ----------------
__global__ void k_cast(const float* __restrict__ x, f16* __restrict__ xh, long n8) {
  long i = blockIdx.x * 256L + threadIdx.x;
  if (i >= n8) return;
  float4 a = ((const float4*)x)[2 * i];
  float4 b = ((const float4*)x)[2 * i + 1];
  half8 o;
  o[0] = (f16)a.x; o[1] = (f16)a.y; o[2] = (f16)a.z; o[3] = (f16)a.w;
  o[4] = (f16)b.x; o[5] = (f16)b.y; o[6] = (f16)b.z; o[7] = (f16)b.w;
  *(half8*)(xh + 8 * i) = o;
}

// ---------------- transpose W [K][Nn] fp32 -> [Nn][K] f16, 64x64 tiles ----------------
__global__ __launch_bounds__(256) void k_transpose(const float* __restrict__ in,
                                                   f16* __restrict__ out, int K, int Nn) {
  __shared__ __attribute__((aligned(16))) f16 T[64][72];
  int n0 = blockIdx.x * 64, k0 = blockIdx.y * 64;
  int t = threadIdx.x;
  int kr = t >> 4, nc = (t & 15) * 4;
  for (int i = 0; i < 4; i++) {
    int k = kr + i * 16;
    float4 v = *(const float4*)&in[(long)(k0 + k) * Nn + n0 + nc];
    T[nc + 0][k] = (f16)v.x;
    T[nc + 1][k] = (f16)v.y;
    T[nc + 2][k] = (f16)v.z;
    T[nc + 3][k] = (f16)v.w;
  }
  __syncthreads();
  for (int i = 0; i < 2; i++) {
    int slot = t + i * 256;
    int n = slot >> 3, ch = (slot & 7) * 8;
    *(half8*)&out[(long)(n0 + n) * K + k0 + ch] = *(half8*)&T[n][ch];
  }
}

// ---------------- fg mask: exact integer bicubic-!=0 ----------------
__global__ void k_fg(const int* __restrict__ mask, unsigned char* __restrict__ fg) {
  int id = blockIdx.x * 256 + threadIdx.x;  // 8*4096
  int b = id >> 12, o = (id >> 6) & 63, p = id & 63;
  const int* mb = mask + (long)b * 65536;
  const int w[4] = {-3, 19, 19, -3};
  int s = 0;
  for (int dh = 0; dh < 4; dh++) {
    const int* row = mb + (4 * o + dh) * 256 + 4 * p;
    int rs = -3 * row[0] + 19 * row[1] + 19 * row[2] - 3 * row[3];
    s += w[dh] * rs;
  }
  fg[id] = (s != 0) ? 1 : 0;
}

// ---------------- K/V projection ----------------
__global__ __launch_bounds__(256) void k_kvproj(const float* __restrict__ ctx,
    const f16* __restrict__ WkT, const f16* __restrict__ WvT,
    f16* __restrict__ kpad, f16* __restrict__ vT) {
  int nb0 = blockIdx.x * 128;
  int b = blockIdx.y;
  int kv = blockIdx.z;
  const f16* WT = kv ? WvT : WkT;
  __shared__ __attribute__((aligned(16))) f16 Clds[CTXP][40];
  __shared__ __attribute__((aligned(16))) f16 Blds[128][40];
  int tid = threadIdx.x;
  int lane = tid & 63, w = tid >> 6;
  int ln = lane & 15, qd = lane >> 4;
  f32x4 acc[6][2] = {};
  for (int k0 = 0; k0 < CDIM; k0 += 32) {
    for (int i = tid; i < CTXP * 32; i += 256) {
      int j = i >> 5, kk = i & 31;
      float v = (j < CTX) ? ctx[((long)b * CTX + j) * CDIM + k0 + kk] : 0.f;
      Clds[j][kk] = (f16)v;
    }
    for (int c = tid; c < 128 * 4; c += 256) {
      int n = c >> 2, kc = (c & 3) * 8;
      *(half8*)&Blds[n][kc] = *(const half8*)&WT[(long)(nb0 + n) * CDIM + k0 + kc];
    }
    __syncthreads();
    half8 bfr[2];
    for (int nt = 0; nt < 2; nt++) bfr[nt] = *(half8*)&Blds[w * 32 + nt * 16 + ln][qd * 8];
    for (int mt = 0; mt < 6; mt++) {
      half8 af = *(half8*)&Clds[mt * 16 + ln][qd * 8];
      for (int nt = 0; nt < 2; nt++)
        acc[mt][nt] = __builtin_amdgcn_mfma_f32_16x16x32_f16(af, bfr[nt], acc[mt][nt], 0, 0, 0);
    }
    __syncthreads();
  }
  for (int mt = 0; mt < 6; mt++)
    for (int nt = 0; nt < 2; nt++) {
      int n = nb0 + w * 32 + nt * 16 + ln;
      if (kv == 0) {
        for (int r = 0; r < 4; r++) {
          int j = mt * 16 + qd * 4 + r;
          kpad[((long)b * CTXP + j) * INNER + n] = (f16)acc[mt][nt][r];
        }
      } else {
        half4v pv;
        for (int r = 0; r < 4; r++) pv[r] = (f16)acc[mt][nt][r];
        *(half4v*)&vT[((long)b * INNER + n) * CTXP + mt * 16 + qd * 4] = pv;
      }
    }
}

// ---------------- big GEMM: m97-style async staging + XOR swizzle ----------------
// 128x128 tile, BK=64, 256 threads (2x2 waves of 64x64). LDS rows are 64 halfs,
// chunk c of row r stored at slot (c ^ (r&7)) -> conflict-free ds_read_b128.
template <int OUT_F32>
__global__ __launch_bounds__(256) void k_gemm(const f16* __restrict__ A,
    const f16* __restrict__ Bt, const float* __restrict__ bias,
    f16* __restrict__ outh, float* __restrict__ outf, int K) {
  __shared__ __attribute__((aligned(16))) f16 Alds[128 * 64];
  __shared__ __attribute__((aligned(16))) f16 Blds[128 * 64];
  int tid = threadIdx.x, lane = tid & 63, w = tid >> 6;
  int wr = w >> 1, wc = w & 1;
  int ln = lane & 15, qd = lane >> 4;
  long m0 = (long)blockIdx.x * 128;
  int n0 = blockIdx.y * 128;
  int srow = lane >> 3;    // 0..7  (row within 8-row group)
  int schunk = lane & 7;   // LDS chunk slot within row
  f32x4 acc[4][4] = {};
  for (int k0 = 0; k0 < K; k0 += 64) {
#pragma unroll
    for (int i = 0; i < 4; i++) {
      int row = w * 32 + i * 8 + srow;
      int ca = (schunk ^ (row & 7)) * 8;  // swizzled source chunk
      gload16(&A[(m0 + row) * K + k0 + ca], &Alds[w * 2048 + i * 512]);
      gload16(&Bt[(long)(n0 + row) * K + k0 + ca], &Blds[w * 2048 + i * 512]);
    }
    __syncthreads();
#pragma unroll
    for (int s = 0; s < 2; s++) {
      half8 af[4], bf[4];
#pragma unroll
      for (int mt = 0; mt < 4; mt++) {
        int row = wr * 64 + mt * 16 + ln;
        af[mt] = *(half8*)&Alds[row * 64 + (((s * 4 + qd) ^ (row & 7)) * 8)];
      }
#pragma unroll
      for (int nt = 0; nt < 4; nt++) {
        int row = wc * 64 + nt * 16 + ln;
        bf[nt] = *(half8*)&Blds[row * 64 + (((s * 4 + qd) ^ (row & 7)) * 8)];
      }
#pragma unroll
      for (int mt = 0; mt < 4; mt++)
#pragma unroll
        for (int nt = 0; nt < 4; nt++)
          acc[mt][nt] = __builtin_amdgcn_mfma_f32_16x16x32_f16(af[mt], bf[nt], acc[mt][nt], 0, 0, 0);
    }
    __syncthreads();
  }
  for (int mt = 0; mt < 4; mt++) {
    long mrow = m0 + wr * 64 + mt * 16 + qd * 4;
    for (int nt = 0; nt < 4; nt++) {
      int n = n0 + wc * 64 + nt * 16 + ln;
      float bv = OUT_F32 ? bias[n] : 0.f;
      for (int r = 0; r < 4; r++) {
        if (OUT_F32) outf[(mrow + r) * INNER + n] = acc[mt][nt][r] + bv;
        else         outh[(mrow + r) * INNER + n] = (f16)acc[mt][nt][r];
      }
    }
  }
}

// ---------------- fused masked attention ----------------
__global__ __launch_bounds__(256) void k_attn(const f16* __restrict__ q,
    const f16* __restrict__ kpad, const f16* __restrict__ vT,
    const unsigned char* __restrict__ fg, f16* __restrict__ ao) {
  int mb = blockIdx.x;
  int h = blockIdx.y;
  int b = blockIdx.z;
  __shared__ __attribute__((aligned(16))) f16 Klds[CTXP][72];
  __shared__ __attribute__((aligned(16))) f16 Vlds[64][104];
  __shared__ __attribute__((aligned(16))) f16 Plds[4][16][104];
  int tid = threadIdx.x, lane = tid & 63, w = tid >> 6;
  int ln = lane & 15, qd = lane >> 4;

  for (int c = tid; c < CTXP * 8; c += 256) {
    int j = c >> 3, kc = (c & 7) * 8;
    *(half8*)&Klds[j][kc] = *(const half8*)&kpad[((long)b * CTXP + j) * INNER + h * 64 + kc];
  }
  for (int c = tid; c < 64 * 12; c += 256) {
    int d = c / 12, jc = (c % 12) * 8;
    *(half8*)&Vlds[d][jc] = *(const half8*)&vT[((long)b * INNER + h * 64 + d) * CTXP + jc];
  }
  __syncthreads();

  long mg = (long)b * SEQ + mb * 64 + w * 16 + ln;
  half8 qf[2];
  for (int s = 0; s < 2; s++)
    qf[s] = *(const half8*)&q[mg * INNER + h * 64 + s * 32 + qd * 8];

  f32x4 sacc[6] = {};
  for (int s = 0; s < 2; s++)
    for (int nt = 0; nt < 6; nt++) {
      half8 bf = *(half8*)&Klds[nt * 16 + ln][s * 32 + qd * 8];
      sacc[nt] = __builtin_amdgcn_mfma_f32_16x16x32_f16(qf[s], bf, sacc[nt], 0, 0, 0);
    }

  unsigned int fgw = *(const unsigned int*)&fg[(long)b * SEQ + mb * 64 + w * 16 + qd * 4];
  const float scale = 0.125f;
  for (int r = 0; r < 4; r++) {
    bool f = ((fgw >> (8 * r)) & 0xff) != 0;
    float vals[6];
    bool oks[6];
    float mx = -1e30f;
    for (int nt = 0; nt < 6; nt++) {
      int j = nt * 16 + ln;
      bool ok = (j < 77) || (j < 81 ? f : (j < 85 ? !f : false));
      float v = sacc[nt][r] * scale;
      vals[nt] = v; oks[nt] = ok;
      if (ok) mx = fmaxf(mx, v);
    }
    for (int d = 1; d < 16; d <<= 1) mx = fmaxf(mx, __shfl_xor(mx, d, 64));
    float sum = 0.f, p[6];
    for (int nt = 0; nt < 6; nt++) {
      p[nt] = oks[nt] ? __expf(vals[nt] - mx) : 0.f;
      sum += p[nt];
    }
    for (int d = 1; d < 16; d <<= 1) sum += __shfl_xor(sum, d, 64);
    float inv = 1.f / sum;
    for (int nt = 0; nt < 6; nt++)
      Plds[w][qd * 4 + r][nt * 16 + ln] = (f16)(p[nt] * inv);
  }
  __syncthreads();

  f32x4 oacc[4] = {};
  for (int ks = 0; ks < 3; ks++) {
    half8 pf = *(half8*)&Plds[w][ln][ks * 32 + qd * 8];
    for (int ntd = 0; ntd < 4; ntd++) {
      half8 vf = *(half8*)&Vlds[ntd * 16 + ln][ks * 32 + qd * 8];
      oacc[ntd] = __builtin_amdgcn_mfma_f32_16x16x32_f16(pf, vf, oacc[ntd], 0, 0, 0);
    }
  }
  // stage O through LDS (per-wave region; same-wave LDS ops are in-order) for
  // coalesced half8 stores
  for (int ntd = 0; ntd < 4; ntd++)
    for (int r = 0; r < 4; r++)
      Plds[w][qd * 4 + r][ntd * 16 + ln] = (f16)oacc[ntd][r];
  __syncthreads();
  long rowbase = (long)b * SEQ + mb * 64 + w * 16;
  for (int i = 0; i < 2; i++) {
    int slot = lane + i * 64;
    int rrow = slot >> 3, ch = (slot & 7) * 8;
    *(half8*)&ao[(rowbase + rrow) * INNER + h * 64 + ch] = *(half8*)&Plds[w][rrow][ch];
  }
}

extern "C" void kernel_launch(void* const* d_in, const int* in_sizes, int n_in,
                              void* d_out, int out_size, void* d_ws, size_t ws_size,
                              hipStream_t stream) {
  const float* x   = (const float*)d_in[0];
  const float* ctx = (const float*)d_in[1];
  const float* Wq  = (const float*)d_in[2];
  const float* Wk  = (const float*)d_in[3];
  const float* Wv  = (const float*)d_in[4];
  const float* Wo  = (const float*)d_in[5];
  const float* bo  = (const float*)d_in[6];
  const int*  mask = (const int*)d_in[7];
  float* out = (float*)d_out;

  char* ws = (char*)d_ws;
  size_t off = 0;
  f16* xh  = (f16*)(ws + off); off += 83886080;   // 8*4096*1280 f16
  f16* q   = (f16*)(ws + off); off += 83886080;
  f16* ao  = (f16*)(ws + off); off += 83886080;
  f16* WqT = (f16*)(ws + off); off += 3276800;
  f16* WoT = (f16*)(ws + off); off += 3276800;
  f16* WkT = (f16*)(ws + off); off += 2621440;
  f16* WvT = (f16*)(ws + off); off += 2621440;
  f16* kpad= (f16*)(ws + off); off += 1966080;    // [8][96][1280]
  f16* vT  = (f16*)(ws + off); off += 1966080;    // [8][1280][96]
  unsigned char* fg = (unsigned char*)(ws + off); off += 32768;
  if (ws_size < off) return;

  k_cast<<<20480, 256, 0, stream>>>(x, xh, 5242880);
  k_transpose<<<dim3(1280/64, 1280/64), 256, 0, stream>>>(Wq, WqT, 1280, 1280);
  k_transpose<<<dim3(1280/64, 1024/64), 256, 0, stream>>>(Wk, WkT, 1024, 1280);
  k_transpose<<<dim3(1280/64, 1024/64), 256, 0, stream>>>(Wv, WvT, 1024, 1280);
  k_transpose<<<dim3(1280/64, 1280/64), 256, 0, stream>>>(Wo, WoT, 1280, 1280);
  k_fg<<<128, 256, 0, stream>>>(mask, fg);
  k_kvproj<<<dim3(10, 8, 2), 256, 0, stream>>>(ctx, WkT, WvT, kpad, vT);
  k_gemm<0><<<dim3(256, 10), 256, 0, stream>>>(xh, WqT, nullptr, q, nullptr, 1280);
  k_attn<<<dim3(64, 20, 8), 256, 0, stream>>>(q, kpad, vT, fg, ao);
  k_gemm<1><<<dim3(256, 10), 256, 0, stream>>>(ao, WoT, bo, nullptr, out, 1280);
}

// Round 3
// 717.401 us; speedup vs baseline: 1.2063x; 1.1963x over previous
//
#include <hip/hip_runtime.h>
#include <math.h>

typedef _Float16 f16;
typedef _Float16 half8 __attribute__((ext_vector_type(8)));
typedef _Float16 half4v __attribute__((ext_vector_type(4)));
typedef float f32x4 __attribute__((ext_vector_type(4)));

#define NB 8
#define SEQ 4096
#define QDIM 1280
#define CDIM 1024
#define INNER 1280
#define CTX 85
#define CTXP 96

__device__ __forceinline__ void gload16(const void* g, void* l) {
  __builtin_amdgcn_global_load_lds(
      (const __attribute__((address_space(1))) unsigned int*)g,
      (__attribute__((address_space(3))) unsigned int*)l, 16, 0, 0);
}

// ---------------- cast x fp32 -> f16 (16B stores) ----------------
__global__ void k_cast(const float* __restrict__ x, f16* __restrict__ xh, long n8) {
  long i = blockIdx.x * 256L + threadIdx.x;
  if (i >= n8) return;
  float4 a = ((const float4*)x)[2 * i];
  float4 b = ((const float4*)x)[2 * i + 1];
  half8 o;
  o[0] = (f16)a.x; o[1] = (f16)a.y; o[2] = (f16)a.z; o[3] = (f16)a.w;
  o[4] = (f16)b.x; o[5] = (f16)b.y; o[6] = (f16)b.z; o[7] = (f16)b.w;
  *(half8*)(xh + 8 * i) = o;
}

// ---------------- cast ctx fp32 -> f16, zero-padded to [8][96][1024] ----------------
__global__ void k_castctx(const float* __restrict__ ctx, f16* __restrict__ ctxh) {
  int id = blockIdx.x * 256 + threadIdx.x;  // 8*96*128
  int b = id / (96 * 128);
  int rem = id % (96 * 128);
  int j = rem >> 7;
  int kc = (rem & 127) * 8;
  half8 o = {};
  if (j < CTX) {
    const float* p = ctx + ((long)b * CTX + j) * CDIM + kc;
    float4 a = *(const float4*)p;
    float4 c = *(const float4*)(p + 4);
    o[0] = (f16)a.x; o[1] = (f16)a.y; o[2] = (f16)a.z; o[3] = (f16)a.w;
    o[4] = (f16)c.x; o[5] = (f16)c.y; o[6] = (f16)c.z; o[7] = (f16)c.w;
  }
  *(half8*)(ctxh + (long)id * 8) = o;
}

// ---------------- transpose W [K][Nn] fp32 -> [Nn][K] f16, 64x64 tiles ----------------
__global__ __launch_bounds__(256) void k_transpose(const float* __restrict__ in,
                                                   f16* __restrict__ out, int K, int Nn) {
  __shared__ __attribute__((aligned(16))) f16 T[64][72];
  int n0 = blockIdx.x * 64, k0 = blockIdx.y * 64;
  int t = threadIdx.x;
  int kr = t >> 4, nc = (t & 15) * 4;
  for (int i = 0; i < 4; i++) {
    int k = kr + i * 16;
    float4 v = *(const float4*)&in[(long)(k0 + k) * Nn + n0 + nc];
    T[nc + 0][k] = (f16)v.x;
    T[nc + 1][k] = (f16)v.y;
    T[nc + 2][k] = (f16)v.z;
    T[nc + 3][k] = (f16)v.w;
  }
  __syncthreads();
  for (int i = 0; i < 2; i++) {
    int slot = t + i * 256;
    int n = slot >> 3, ch = (slot & 7) * 8;
    *(half8*)&out[(long)(n0 + n) * K + k0 + ch] = *(half8*)&T[n][ch];
  }
}

// ---------------- fg mask: exact integer bicubic-!=0 ----------------
__global__ void k_fg(const int* __restrict__ mask, unsigned char* __restrict__ fg) {
  int id = blockIdx.x * 256 + threadIdx.x;  // 8*4096
  int b = id >> 12, o = (id >> 6) & 63, p = id & 63;
  const int* mb = mask + (long)b * 65536;
  const int w[4] = {-3, 19, 19, -3};
  int s = 0;
  for (int dh = 0; dh < 4; dh++) {
    const int* row = mb + (4 * o + dh) * 256 + 4 * p;
    int rs = -3 * row[0] + 19 * row[1] + 19 * row[2] - 3 * row[3];
    s += w[dh] * rs;
  }
  fg[id] = (s != 0) ? 1 : 0;
}

// ---------------- K/V projection: register-only skinny GEMM ----------------
// grid (20, 8, 2) x 256 threads; wave w computes a 96x16 output stripe,
// n-tile = blockIdx.x*4 + w. No LDS, no barriers; ILP hides L2 latency.
__global__ __launch_bounds__(256) void k_kvproj(const f16* __restrict__ ctxh,
    const f16* __restrict__ WkT, const f16* __restrict__ WvT,
    f16* __restrict__ kpad, f16* __restrict__ vT) {
  int b = blockIdx.y, kv = blockIdx.z;
  const f16* WT = kv ? WvT : WkT;
  int w = threadIdx.x >> 6, lane = threadIdx.x & 63;
  int ln = lane & 15, qd = lane >> 4;
  int n0 = (blockIdx.x * 4 + w) * 16;
  const f16* arow = ctxh + ((long)b * CTXP + ln) * CDIM + qd * 8;
  const f16* brow = WT + (long)(n0 + ln) * CDIM + qd * 8;
  f32x4 acc[6] = {};
#pragma unroll 4
  for (int k0 = 0; k0 < CDIM; k0 += 32) {
    half8 bf = *(const half8*)(brow + k0);
#pragma unroll
    for (int mt = 0; mt < 6; mt++) {
      half8 af = *(const half8*)(arow + mt * 16 * CDIM + k0);
      acc[mt] = __builtin_amdgcn_mfma_f32_16x16x32_f16(af, bf, acc[mt], 0, 0, 0);
    }
  }
  if (kv == 0) {
    for (int mt = 0; mt < 6; mt++)
      for (int r = 0; r < 4; r++)
        kpad[((long)b * CTXP + mt * 16 + qd * 4 + r) * INNER + n0 + ln] = (f16)acc[mt][r];
  } else {
    for (int mt = 0; mt < 6; mt++) {
      half4v pv;
      for (int r = 0; r < 4; r++) pv[r] = (f16)acc[mt][r];
      *(half4v*)&vT[((long)b * INNER + n0 + ln) * CTXP + mt * 16 + qd * 4] = pv;
    }
  }
}

// ---------------- big GEMM: m97-style async staging + XOR swizzle ----------------
// 128x128 tile, BK=64, 256 threads (2x2 waves of 64x64). LDS rows are 64 halfs,
// chunk c of row r stored at slot (c ^ (r&7)) -> conflict-free ds_read_b128.
template <int OUT_F32>
__global__ __launch_bounds__(256) void k_gemm(const f16* __restrict__ A,
    const f16* __restrict__ Bt, const float* __restrict__ bias,
    f16* __restrict__ outh, float* __restrict__ outf, int K) {
  __shared__ __attribute__((aligned(16))) f16 Alds[128 * 64];
  __shared__ __attribute__((aligned(16))) f16 Blds[128 * 64];
  int tid = threadIdx.x, lane = tid & 63, w = tid >> 6;
  int wr = w >> 1, wc = w & 1;
  int ln = lane & 15, qd = lane >> 4;
  long m0 = (long)blockIdx.x * 128;
  int n0 = blockIdx.y * 128;
  int srow = lane >> 3;    // 0..7  (row within 8-row group)
  int schunk = lane & 7;   // LDS chunk slot within row
  f32x4 acc[4][4] = {};
  for (int k0 = 0; k0 < K; k0 += 64) {
#pragma unroll
    for (int i = 0; i < 4; i++) {
      int row = w * 32 + i * 8 + srow;
      int ca = (schunk ^ (row & 7)) * 8;  // swizzled source chunk
      gload16(&A[(m0 + row) * K + k0 + ca], &Alds[w * 2048 + i * 512]);
      gload16(&Bt[(long)(n0 + row) * K + k0 + ca], &Blds[w * 2048 + i * 512]);
    }
    __syncthreads();
#pragma unroll
    for (int s = 0; s < 2; s++) {
      half8 af[4], bf[4];
#pragma unroll
      for (int mt = 0; mt < 4; mt++) {
        int row = wr * 64 + mt * 16 + ln;
        af[mt] = *(half8*)&Alds[row * 64 + (((s * 4 + qd) ^ (row & 7)) * 8)];
      }
#pragma unroll
      for (int nt = 0; nt < 4; nt++) {
        int row = wc * 64 + nt * 16 + ln;
        bf[nt] = *(half8*)&Blds[row * 64 + (((s * 4 + qd) ^ (row & 7)) * 8)];
      }
#pragma unroll
      for (int mt = 0; mt < 4; mt++)
#pragma unroll
        for (int nt = 0; nt < 4; nt++)
          acc[mt][nt] = __builtin_amdgcn_mfma_f32_16x16x32_f16(af[mt], bf[nt], acc[mt][nt], 0, 0, 0);
    }
    __syncthreads();
  }
  for (int mt = 0; mt < 4; mt++) {
    long mrow = m0 + wr * 64 + mt * 16 + qd * 4;
    for (int nt = 0; nt < 4; nt++) {
      int n = n0 + wc * 64 + nt * 16 + ln;
      float bv = OUT_F32 ? bias[n] : 0.f;
      for (int r = 0; r < 4; r++) {
        if (OUT_F32) outf[(mrow + r) * INNER + n] = acc[mt][nt][r] + bv;
        else         outh[(mrow + r) * INNER + n] = (f16)acc[mt][nt][r];
      }
    }
  }
}

// ---------------- fused masked attention ----------------
__global__ __launch_bounds__(256) void k_attn(const f16* __restrict__ q,
    const f16* __restrict__ kpad, const f16* __restrict__ vT,
    const unsigned char* __restrict__ fg, f16* __restrict__ ao) {
  int mb = blockIdx.x;
  int h = blockIdx.y;
  int b = blockIdx.z;
  __shared__ __attribute__((aligned(16))) f16 Klds[CTXP][72];
  __shared__ __attribute__((aligned(16))) f16 Vlds[64][104];
  __shared__ __attribute__((aligned(16))) f16 Plds[4][16][104];
  int tid = threadIdx.x, lane = tid & 63, w = tid >> 6;
  int ln = lane & 15, qd = lane >> 4;

  for (int c = tid; c < CTXP * 8; c += 256) {
    int j = c >> 3, kc = (c & 7) * 8;
    *(half8*)&Klds[j][kc] = *(const half8*)&kpad[((long)b * CTXP + j) * INNER + h * 64 + kc];
  }
  for (int c = tid; c < 64 * 12; c += 256) {
    int d = c / 12, jc = (c % 12) * 8;
    *(half8*)&Vlds[d][jc] = *(const half8*)&vT[((long)b * INNER + h * 64 + d) * CTXP + jc];
  }
  __syncthreads();

  long mg = (long)b * SEQ + mb * 64 + w * 16 + ln;
  half8 qf[2];
  for (int s = 0; s < 2; s++)
    qf[s] = *(const half8*)&q[mg * INNER + h * 64 + s * 32 + qd * 8];

  f32x4 sacc[6] = {};
  for (int s = 0; s < 2; s++)
    for (int nt = 0; nt < 6; nt++) {
      half8 bf = *(half8*)&Klds[nt * 16 + ln][s * 32 + qd * 8];
      sacc[nt] = __builtin_amdgcn_mfma_f32_16x16x32_f16(qf[s], bf, sacc[nt], 0, 0, 0);
    }

  unsigned int fgw = *(const unsigned int*)&fg[(long)b * SEQ + mb * 64 + w * 16 + qd * 4];
  const float scale = 0.125f;
  for (int r = 0; r < 4; r++) {
    bool f = ((fgw >> (8 * r)) & 0xff) != 0;
    float vals[6];
    bool oks[6];
    float mx = -1e30f;
    for (int nt = 0; nt < 6; nt++) {
      int j = nt * 16 + ln;
      bool ok = (j < 77) || (j < 81 ? f : (j < 85 ? !f : false));
      float v = sacc[nt][r] * scale;
      vals[nt] = v; oks[nt] = ok;
      if (ok) mx = fmaxf(mx, v);
    }
    for (int d = 1; d < 16; d <<= 1) mx = fmaxf(mx, __shfl_xor(mx, d, 64));
    float sum = 0.f, p[6];
    for (int nt = 0; nt < 6; nt++) {
      p[nt] = oks[nt] ? __expf(vals[nt] - mx) : 0.f;
      sum += p[nt];
    }
    for (int d = 1; d < 16; d <<= 1) sum += __shfl_xor(sum, d, 64);
    float inv = 1.f / sum;
    for (int nt = 0; nt < 6; nt++)
      Plds[w][qd * 4 + r][nt * 16 + ln] = (f16)(p[nt] * inv);
  }
  __syncthreads();

  f32x4 oacc[4] = {};
  for (int ks = 0; ks < 3; ks++) {
    half8 pf = *(half8*)&Plds[w][ln][ks * 32 + qd * 8];
    for (int ntd = 0; ntd < 4; ntd++) {
      half8 vf = *(half8*)&Vlds[ntd * 16 + ln][ks * 32 + qd * 8];
      oacc[ntd] = __builtin_amdgcn_mfma_f32_16x16x32_f16(pf, vf, oacc[ntd], 0, 0, 0);
    }
  }
  // stage O through LDS for coalesced half8 stores
  for (int ntd = 0; ntd < 4; ntd++)
    for (int r = 0; r < 4; r++)
      Plds[w][qd * 4 + r][ntd * 16 + ln] = (f16)oacc[ntd][r];
  __syncthreads();
  long rowbase = (long)b * SEQ + mb * 64 + w * 16;
  for (int i = 0; i < 2; i++) {
    int slot = lane + i * 64;
    int rrow = slot >> 3, ch = (slot & 7) * 8;
    *(half8*)&ao[(rowbase + rrow) * INNER + h * 64 + ch] = *(half8*)&Plds[w][rrow][ch];
  }
}

extern "C" void kernel_launch(void* const* d_in, const int* in_sizes, int n_in,
                              void* d_out, int out_size, void* d_ws, size_t ws_size,
                              hipStream_t stream) {
  const float* x   = (const float*)d_in[0];
  const float* ctx = (const float*)d_in[1];
  const float* Wq  = (const float*)d_in[2];
  const float* Wk  = (const float*)d_in[3];
  const float* Wv  = (const float*)d_in[4];
  const float* Wo  = (const float*)d_in[5];
  const float* bo  = (const float*)d_in[6];
  const int*  mask = (const int*)d_in[7];
  float* out = (float*)d_out;

  char* ws = (char*)d_ws;
  size_t off = 0;
  f16* xh  = (f16*)(ws + off); off += 83886080;   // 8*4096*1280 f16
  f16* q   = (f16*)(ws + off); off += 83886080;
  f16* ao  = (f16*)(ws + off); off += 83886080;
  f16* WqT = (f16*)(ws + off); off += 3276800;
  f16* WoT = (f16*)(ws + off); off += 3276800;
  f16* WkT = (f16*)(ws + off); off += 2621440;
  f16* WvT = (f16*)(ws + off); off += 2621440;
  f16* kpad= (f16*)(ws + off); off += 1966080;    // [8][96][1280]
  f16* vT  = (f16*)(ws + off); off += 1966080;    // [8][1280][96]
  f16* ctxh= (f16*)(ws + off); off += 1572864;    // [8][96][1024] zero-padded
  unsigned char* fg = (unsigned char*)(ws + off); off += 32768;
  if (ws_size < off) return;

  k_cast<<<20480, 256, 0, stream>>>(x, xh, 5242880);
  k_castctx<<<384, 256, 0, stream>>>(ctx, ctxh);
  k_transpose<<<dim3(1280/64, 1280/64), 256, 0, stream>>>(Wq, WqT, 1280, 1280);
  k_transpose<<<dim3(1280/64, 1024/64), 256, 0, stream>>>(Wk, WkT, 1024, 1280);
  k_transpose<<<dim3(1280/64, 1024/64), 256, 0, stream>>>(Wv, WvT, 1024, 1280);
  k_transpose<<<dim3(1280/64, 1280/64), 256, 0, stream>>>(Wo, WoT, 1280, 1280);
  k_fg<<<128, 256, 0, stream>>>(mask, fg);
  k_kvproj<<<dim3(20, 8, 2), 256, 0, stream>>>(ctxh, WkT, WvT, kpad, vT);
  k_gemm<0><<<dim3(256, 10), 256, 0, stream>>>(xh, WqT, nullptr, q, nullptr, 1280);
  k_attn<<<dim3(64, 20, 8), 256, 0, stream>>>(q, kpad, vT, fg, ao);
  k_gemm<1><<<dim3(256, 10), 256, 0, stream>>>(ao, WoT, bo, nullptr, out, 1280);
}